// Round 6
// baseline (162.721 us; speedup 1.0000x reference)
//
#include <hip/hip_runtime.h>
#include <hip/hip_cooperative_groups.h>
#include <math.h>

namespace cg = cooperative_groups;

#define EPS 1e-12f
#define NN 8
#define TT 2048
#define DD 512
#define KK 64

typedef short short8 __attribute__((ext_vector_type(8)));
typedef float floatx4 __attribute__((ext_vector_type(4)));

__device__ __forceinline__ unsigned short f2bf(float f) {
    unsigned int u = __float_as_uint(f);
    u += 0x7FFFu + ((u >> 16) & 1u);
    return (unsigned short)(u >> 16);
}
__device__ __forceinline__ unsigned int pack2(float a, float b) {
    return (unsigned int)f2bf(a) | ((unsigned int)f2bf(b) << 16);
}

// ---------------------------------------------------------------------------
// ws layout (float units):
//   xb    bf16 [N*T][D]       @ 0        (4194304)   raw x, bf16
//   aTs   bf16 [N][K][T]      @ 4194304  (524288)    a * s_t
//   part  f32  [8tc][512nk][D]@ 4718592  (2097152)
//   asumP f32  [256blk][64k]  @ 6815744  (16384)     per-block unscaled a sums
// total 6832128 floats = 27.3 MB
// ---------------------------------------------------------------------------

// One cooperative kernel, grid 256 x 256 (1 block/CU), two grid.sync()s.
// Phase A: W->bf16 LDS (fragment-packed) + x L2-norm + assignment softmax.
// Phase B: vlad contraction, 128-d-wide tile per block (a-frags reused 8x).
// Phase C: asum reduce + part reduce - asum*c + intra-norm, global norm = 8.
__global__ __launch_bounds__(256) void mega(const float* __restrict__ x,
                                            const float* __restrict__ W,
                                            const float* __restrict__ bias,
                                            const float* __restrict__ cent,
                                            unsigned short* __restrict__ xb,
                                            unsigned short* __restrict__ aTs,
                                            float* __restrict__ part,
                                            float* __restrict__ asumP,
                                            float* __restrict__ out) {
    __shared__ __align__(16) unsigned char smem[66560];
    cg::grid_group gg_ = cg::this_grid();

    const int tid = threadIdx.x;
    const int bid = blockIdx.x;
    const int w = tid >> 6, lane = tid & 63;
    const int l = lane & 15, q = lane >> 4;

    // ========================= Phase A =========================
    {
        unsigned short* sW = (unsigned short*)smem;          // 65536 B
        float* sRed = (float*)(smem + 65536);                // 1024 B

        const int row0 = bid * 64 + w * 16;
        const int row = row0 + l;
        const int n = row0 >> 11;
        const int tl0 = row0 & (TT - 1);

        const float* xr = x + (size_t)row * DD;
        unsigned short* xo = xb + (size_t)row * DD;
        short8 fragA[16];
        float ssq = 0.0f;
#pragma unroll
        for (int s = 0; s < 16; ++s) {
            float4 u0 = *(const float4*)(xr + s * 32 + q * 8);
            float4 u1 = *(const float4*)(xr + s * 32 + q * 8 + 4);
            ssq += u0.x*u0.x + u0.y*u0.y + u0.z*u0.z + u0.w*u0.w
                 + u1.x*u1.x + u1.y*u1.y + u1.z*u1.z + u1.w*u1.w;
            uint4 pk;
            pk.x = pack2(u0.x, u0.y); pk.y = pack2(u0.z, u0.w);
            pk.z = pack2(u1.x, u1.y); pk.w = pack2(u1.z, u1.w);
            union { uint4 u; short8 s8; } cvt; cvt.u = pk;
            fragA[s] = cvt.s8;
            *(uint4*)(xo + s * 32 + q * 8) = pk;
        }

        // W -> LDS (fragment-packed: slot ((s*4+h)*64+lane) = 8 bf16)
        {
            const int sp = tid >> 4, hp = (tid >> 2) & 3, qp = tid & 3;
            const float* wsrc = W + (size_t)(hp * 16) * DD + sp * 32 + qp * 8;
            unsigned short* wdst = sW + (size_t)tid * 128;
#pragma unroll
            for (int j = 0; j < 16; ++j) {
                float4 u0 = *(const float4*)(wsrc + (size_t)j * DD);
                float4 u1 = *(const float4*)(wsrc + (size_t)j * DD + 4);
                uint4 pk;
                pk.x = pack2(u0.x, u0.y); pk.y = pack2(u0.z, u0.w);
                pk.z = pack2(u1.x, u1.y); pk.w = pack2(u1.z, u1.w);
                *(uint4*)(wdst + j * 8) = pk;
            }
        }

        ssq += __shfl_xor(ssq, 16, 64);
        ssq += __shfl_xor(ssq, 32, 64);
        float st = 1.0f / fmaxf(sqrtf(ssq), EPS);

        __syncthreads();

        floatx4 acc[4];
#pragma unroll
        for (int h = 0; h < 4; ++h) acc[h] = floatx4{0.f, 0.f, 0.f, 0.f};
#pragma unroll
        for (int s = 0; s < 16; ++s) {
#pragma unroll
            for (int h = 0; h < 4; ++h) {
                short8 wf = *(const short8*)(sW + ((size_t)((s * 4 + h) * 64) + lane) * 8);
                acc[h] = __builtin_amdgcn_mfma_f32_16x16x32_bf16(fragA[s], wf, acc[h], 0, 0, 0);
            }
        }

        float sr[4];
#pragma unroll
        for (int r = 0; r < 4; ++r) sr[r] = __shfl(st, 4 * q + r, 64);
        float bj[4];
#pragma unroll
        for (int h = 0; h < 4; ++h) bj[h] = bias[h * 16 + l];

        float av[4][4];
#pragma unroll
        for (int r = 0; r < 4; ++r) {
            float v0 = acc[0][r] * sr[r] + bj[0], v1 = acc[1][r] * sr[r] + bj[1];
            float v2 = acc[2][r] * sr[r] + bj[2], v3 = acc[3][r] * sr[r] + bj[3];
            float m = fmaxf(fmaxf(v0, v1), fmaxf(v2, v3));
#pragma unroll
            for (int msk = 1; msk <= 8; msk <<= 1) m = fmaxf(m, __shfl_xor(m, msk, 64));
            float e0 = __expf(v0 - m), e1 = __expf(v1 - m), e2 = __expf(v2 - m), e3 = __expf(v3 - m);
            float ss = e0 + e1 + e2 + e3;
#pragma unroll
            for (int msk = 1; msk <= 8; msk <<= 1) ss += __shfl_xor(ss, msk, 64);
            float inv = 1.0f / ss;
            av[0][r] = e0 * inv; av[1][r] = e1 * inv; av[2][r] = e2 * inv; av[3][r] = e3 * inv;
        }

#pragma unroll
        for (int h = 0; h < 4; ++h) {
            uint2 p;
            p.x = pack2(av[h][0] * sr[0], av[h][1] * sr[1]);
            p.y = pack2(av[h][2] * sr[2], av[h][3] * sr[3]);
            *(uint2*)(aTs + ((size_t)(n * KK + h * 16 + l)) * TT + tl0 + 4 * q) = p;
        }

#pragma unroll
        for (int h = 0; h < 4; ++h) {
            float sh = av[h][0] + av[h][1] + av[h][2] + av[h][3];
            sh += __shfl_xor(sh, 16, 64);
            sh += __shfl_xor(sh, 32, 64);
            if (q == 0) sRed[w * 64 + h * 16 + l] = sh;
        }
        __syncthreads();
        if (tid < 64) {
            float s0 = sRed[tid] + sRed[64 + tid] + sRed[128 + tid] + sRed[192 + tid];
            asumP[(size_t)bid * 64 + tid] = s0;
        }
    }

    gg_.sync();

    // ========================= Phase B =========================
    // Block (n, tc, dt0): d-columns [dt0*64, dt0*64+64) and [dt0*64+256, +320).
    {
        unsigned short* sX0 = (unsigned short*)smem;   // 128d x 64t, swizzled
        unsigned short* sX1 = sX0 + 8192;
        float* sT = (float*)smem;                      // 64k x 132

        const int low = bid & 63;
        const int n = low >> 3, tc = low & 7, dt0 = bid >> 6;  // dt0 in 0..3

        const int ts = tid & 63, dq = tid >> 6;
        const unsigned short* xbase = xb + ((size_t)(n * TT + tc * 256)) * DD + dt0 * 64 + dq * 16;
        const int g = ts >> 3, t7 = ts & 7;

#define STAGE(S, BUF)                                                          \
    {                                                                          \
        const unsigned short* p_ = xbase + (size_t)((S) * 64 + ts) * DD;       \
        unsigned short vals[32];                                               \
        *(uint4*)(vals)      = *(const uint4*)(p_);                            \
        *(uint4*)(vals + 8)  = *(const uint4*)(p_ + 8);                        \
        *(uint4*)(vals + 16) = *(const uint4*)(p_ + 256);                      \
        *(uint4*)(vals + 24) = *(const uint4*)(p_ + 256 + 8);                  \
        _Pragma("unroll")                                                      \
        for (int e = 0; e < 16; ++e) {                                         \
            int d_ = dq * 16 + e;                                              \
            (BUF)[d_ * 64 + ((g ^ (d_ & 7)) << 3) + t7] = vals[e];             \
        }                                                                      \
        _Pragma("unroll")                                                      \
        for (int e = 0; e < 16; ++e) {                                         \
            int d_ = 64 + dq * 16 + e;                                         \
            (BUF)[d_ * 64 + ((g ^ (d_ & 7)) << 3) + t7] = vals[16 + e];        \
        }                                                                      \
    }

        floatx4 acc[8];
#pragma unroll
        for (int nt = 0; nt < 8; ++nt) acc[nt] = floatx4{0.f, 0.f, 0.f, 0.f};
        const unsigned short* abase = aTs + ((size_t)(n * KK + w * 16 + l)) * TT + tc * 256;

        STAGE(0, sX0);
        __syncthreads();
#pragma unroll
        for (int s = 0; s < 4; ++s) {
            unsigned short* cur = (s & 1) ? sX1 : sX0;
            unsigned short* nxt = (s & 1) ? sX0 : sX1;
            if (s < 3) {
                if (s == 0) STAGE(1, nxt)
                else if (s == 1) STAGE(2, nxt)
                else STAGE(3, nxt)
            }
#pragma unroll
            for (int kb = 0; kb < 2; ++kb) {
                short8 af = *(const short8*)(abase + s * 64 + kb * 32 + q * 8);
                int ggi = q + 4 * kb;
#pragma unroll
                for (int nt = 0; nt < 8; ++nt) {
                    int d = nt * 16 + l;
                    short8 bf = *(const short8*)(cur + d * 64 + ((ggi ^ (d & 7)) << 3));
                    acc[nt] = __builtin_amdgcn_mfma_f32_16x16x32_bf16(af, bf, acc[nt], 0, 0, 0);
                }
            }
            __syncthreads();
        }
#undef STAGE

        // transpose C through LDS -> coalesced stores (two 64-d runs per k)
#pragma unroll
        for (int nt = 0; nt < 8; ++nt)
#pragma unroll
            for (int r = 0; r < 4; ++r)
                sT[(w * 16 + 4 * q + r) * 132 + nt * 16 + l] = acc[nt][r];
        __syncthreads();

        float* pbase = part + ((size_t)(tc * 512 + n * KK)) * DD + dt0 * 64;
        const int fq = tid & 31, kr = tid >> 5;
#pragma unroll
        for (int i = 0; i < 8; ++i) {
            int k = i * 8 + kr;
            int dl = fq * 4;
            int off = dl + ((dl >> 6) * 192);  // 0..63 -> same; 64..127 -> +256 base
            float4 val = *(float4*)(sT + k * 132 + dl);
            *(float4*)(pbase + (size_t)k * DD + off) = val;
        }
        __syncthreads();
    }

    gg_.sync();

    // ========================= Phase C =========================
    // 2 nk per block (128 threads each). Global norm over 64 intra-normalized
    // clusters == 8 (deviation <1e-6 rel -> ~1e-8 on outputs).
    {
        float* sAsum = (float*)smem;        // [2]
        float* sRedC = (float*)smem + 8;    // [4]

        const int half = tid >> 7, lt = tid & 127;
        const int nk = bid * 2 + half;
        const int n = nk >> 6, k = nk & 63;

        if (lt < 32) {
            float p = asumP[(size_t)(n * 32 + lt) * 64 + k];
#pragma unroll
            for (int m = 16; m >= 1; m >>= 1) p += __shfl_xor(p, m, 64);
            if (lt == 0) sAsum[half] = p;
        }
        __syncthreads();
        float as = sAsum[half];

        float4 cc = ((const float4*)(cent + (size_t)k * DD))[lt];
        float4 a4 = make_float4(-as * cc.x, -as * cc.y, -as * cc.z, -as * cc.w);
#pragma unroll
        for (int tc = 0; tc < 8; ++tc) {
            float4 p = ((const float4*)(part + ((size_t)(tc * 512 + nk)) * DD))[lt];
            a4.x += p.x; a4.y += p.y; a4.z += p.z; a4.w += p.w;
        }
        float ssq = a4.x*a4.x + a4.y*a4.y + a4.z*a4.z + a4.w*a4.w;
#pragma unroll
        for (int m = 32; m >= 1; m >>= 1) ssq += __shfl_xor(ssq, m, 64);
        const int wave = tid >> 6;
        if ((tid & 63) == 0) sRedC[wave] = ssq;
        __syncthreads();
        float nr = sqrtf(sRedC[2 * half] + sRedC[2 * half + 1]);
        float sc = 1.0f / (fmaxf(nr, EPS) * 8.0f);
        a4.x *= sc; a4.y *= sc; a4.z *= sc; a4.w *= sc;
        ((float4*)(out + (size_t)nk * DD))[lt] = a4;
    }
}

extern "C" void kernel_launch(void* const* d_in, const int* in_sizes, int n_in,
                              void* d_out, int out_size, void* d_ws, size_t ws_size,
                              hipStream_t stream) {
    const float* x    = (const float*)d_in[0];
    const float* W    = (const float*)d_in[1];
    const float* b    = (const float*)d_in[2];
    const float* cent = (const float*)d_in[3];
    float* out = (float*)d_out;

    float* w = (float*)d_ws;
    unsigned short* xb  = (unsigned short*)(w + 0);
    unsigned short* aTs = (unsigned short*)(w + 4194304);
    float* part  = w + 4718592;
    float* asumP = w + 6815744;

    void* args[] = {(void*)&x, (void*)&W, (void*)&b, (void*)&cent,
                    (void*)&xb, (void*)&aTs, (void*)&part, (void*)&asumP,
                    (void*)&out};
    hipLaunchCooperativeKernel((const void*)mega, dim3(256), dim3(256),
                               args, 0, stream);
}

// Round 7
// 111.701 us; speedup vs baseline: 1.4568x; 1.4568x over previous
//
#include <hip/hip_runtime.h>
#include <math.h>

#define EPS 1e-12f
#define NN 8
#define TT 2048
#define DD 512
#define KK 64

typedef short short8 __attribute__((ext_vector_type(8)));
typedef float floatx4 __attribute__((ext_vector_type(4)));

__device__ __forceinline__ unsigned short f2bf(float f) {
    unsigned int u = __float_as_uint(f);
    u += 0x7FFFu + ((u >> 16) & 1u);
    return (unsigned short)(u >> 16);
}
__device__ __forceinline__ unsigned int pack2(float a, float b) {
    return (unsigned int)f2bf(a) | ((unsigned int)f2bf(b) << 16);
}

// ---------------------------------------------------------------------------
// ws layout (float units):
//   xbT   bf16 [N][D][T]   @ 0        (4194304)   raw x bf16, transposed
//   aTs   bf16 [N][K][T]   @ 4194304  (524288)    a * s_t
//   vpre  f32  [512nk][D]  @ 4718592  (262144)    v before normalization
//   asumP f32  [256][64]   @ 4980736  (16384)
//   norms f32  [512]       @ 4997120  (512)       ssq per (n,k), atomic
// total ~5.0 M floats = 20 MB
// ---------------------------------------------------------------------------

// kA: W->bf16 LDS (fragment-packed) + L2-norm + assignment softmax + x
// transpose to xbT. Grid 256 x 256 thr (4 waves x 16 t-rows).
__global__ __launch_bounds__(256) void kA(const float* __restrict__ x,
                                          const float* __restrict__ W,
                                          const float* __restrict__ bias,
                                          unsigned short* __restrict__ xbT,
                                          unsigned short* __restrict__ aTs,
                                          float* __restrict__ asumP,
                                          float* __restrict__ norms) {
    __shared__ __align__(16) unsigned char smem[67584];
    unsigned short* sW = (unsigned short*)smem;          // 64 KB (phase 1)
    unsigned short* sT = (unsigned short*)smem;          // 66560 B (phase 2, reuse)
    float* sRed = (float*)(smem + 66560);                // 1 KB

    const int tid = threadIdx.x;
    const int bid = blockIdx.x;
    const int w = tid >> 6, lane = tid & 63;
    const int l = lane & 15, q = lane >> 4;
    const int row0 = bid * 64 + w * 16;
    const int row = row0 + l;
    const int n = row0 >> 11;
    const int tl0 = row0 & (TT - 1);
    const int tblk = (bid * 64) & (TT - 1);   // block's t base within n

    // ---- x load (raw bf16 kept in regs) ----
    const float* xr = x + (size_t)row * DD;
    short8 fragA[16];
    float ssq = 0.0f;
#pragma unroll
    for (int s = 0; s < 16; ++s) {
        float4 u0 = *(const float4*)(xr + s * 32 + q * 8);
        float4 u1 = *(const float4*)(xr + s * 32 + q * 8 + 4);
        ssq += u0.x*u0.x + u0.y*u0.y + u0.z*u0.z + u0.w*u0.w
             + u1.x*u1.x + u1.y*u1.y + u1.z*u1.z + u1.w*u1.w;
        uint4 pk;
        pk.x = pack2(u0.x, u0.y); pk.y = pack2(u0.z, u0.w);
        pk.z = pack2(u1.x, u1.y); pk.w = pack2(u1.z, u1.w);
        union { uint4 u; short8 s8; } cvt; cvt.u = pk;
        fragA[s] = cvt.s8;
    }

    // ---- W -> sW (fragment-packed) ----
    {
        const int sp = tid >> 4, hp = (tid >> 2) & 3, qp = tid & 3;
        const float* wsrc = W + (size_t)(hp * 16) * DD + sp * 32 + qp * 8;
        unsigned short* wdst = sW + (size_t)tid * 128;
#pragma unroll
        for (int j = 0; j < 16; ++j) {
            float4 u0 = *(const float4*)(wsrc + (size_t)j * DD);
            float4 u1 = *(const float4*)(wsrc + (size_t)j * DD + 4);
            uint4 pk;
            pk.x = pack2(u0.x, u0.y); pk.y = pack2(u0.z, u0.w);
            pk.z = pack2(u1.x, u1.y); pk.w = pack2(u1.z, u1.w);
            *(uint4*)(wdst + j * 8) = pk;
        }
    }

    ssq += __shfl_xor(ssq, 16, 64);
    ssq += __shfl_xor(ssq, 32, 64);
    float st = 1.0f / fmaxf(sqrtf(ssq), EPS);

    __syncthreads();  // sW ready

    // ---- logits MFMA ----
    floatx4 acc[4];
#pragma unroll
    for (int h = 0; h < 4; ++h) acc[h] = floatx4{0.f, 0.f, 0.f, 0.f};
#pragma unroll
    for (int s = 0; s < 16; ++s) {
#pragma unroll
        for (int h = 0; h < 4; ++h) {
            short8 wf = *(const short8*)(sW + ((size_t)((s * 4 + h) * 64) + lane) * 8);
            acc[h] = __builtin_amdgcn_mfma_f32_16x16x32_bf16(fragA[s], wf, acc[h], 0, 0, 0);
        }
    }

    float sr[4];
#pragma unroll
    for (int r = 0; r < 4; ++r) sr[r] = __shfl(st, 4 * q + r, 64);
    float bj[4];
#pragma unroll
    for (int h = 0; h < 4; ++h) bj[h] = bias[h * 16 + l];

    float av[4][4];
#pragma unroll
    for (int r = 0; r < 4; ++r) {
        float v0 = acc[0][r] * sr[r] + bj[0], v1 = acc[1][r] * sr[r] + bj[1];
        float v2 = acc[2][r] * sr[r] + bj[2], v3 = acc[3][r] * sr[r] + bj[3];
        float m = fmaxf(fmaxf(v0, v1), fmaxf(v2, v3));
#pragma unroll
        for (int msk = 1; msk <= 8; msk <<= 1) m = fmaxf(m, __shfl_xor(m, msk, 64));
        float e0 = __expf(v0 - m), e1 = __expf(v1 - m), e2 = __expf(v2 - m), e3 = __expf(v3 - m);
        float ss = e0 + e1 + e2 + e3;
#pragma unroll
        for (int msk = 1; msk <= 8; msk <<= 1) ss += __shfl_xor(ss, msk, 64);
        float inv = 1.0f / ss;
        av[0][r] = e0 * inv; av[1][r] = e1 * inv; av[2][r] = e2 * inv; av[3][r] = e3 * inv;
    }

    // aTs[n][k][t] = a * s_t
#pragma unroll
    for (int h = 0; h < 4; ++h) {
        uint2 p;
        p.x = pack2(av[h][0] * sr[0], av[h][1] * sr[1]);
        p.y = pack2(av[h][2] * sr[2], av[h][3] * sr[3]);
        *(uint2*)(aTs + ((size_t)(n * KK + h * 16 + l)) * TT + tl0 + 4 * q) = p;
    }

    // per-block unscaled-a k-sums
#pragma unroll
    for (int h = 0; h < 4; ++h) {
        float sh = av[h][0] + av[h][1] + av[h][2] + av[h][3];
        sh += __shfl_xor(sh, 16, 64);
        sh += __shfl_xor(sh, 32, 64);
        if (q == 0) sRed[w * 64 + h * 16 + l] = sh;
    }
    __syncthreads();  // all sW reads done + sRed ready
    if (tid < 64) {
        float s0 = sRed[tid] + sRed[64 + tid] + sRed[128 + tid] + sRed[192 + tid];
        asumP[(size_t)bid * 64 + tid] = s0;
    }

    // ---- transpose fragA -> xbT[n][d][t] via sT [64t][520d] ----
#pragma unroll
    for (int s = 0; s < 16; ++s)
        *(short8*)(sT + (size_t)(w * 16 + l) * 520 + s * 32 + q * 8) = fragA[s];
    __syncthreads();

#pragma unroll
    for (int c = 0; c < 2; ++c) {
        int d = tid + c * 256;
        const unsigned short* colb = sT + d;
        unsigned short* ob = xbT + ((size_t)(n * DD + d)) * TT + tblk;
#pragma unroll
        for (int jj = 0; jj < 8; ++jj) {
            uint4 pk;
            pk.x = (unsigned int)colb[(jj * 8 + 0) * 520] | ((unsigned int)colb[(jj * 8 + 1) * 520] << 16);
            pk.y = (unsigned int)colb[(jj * 8 + 2) * 520] | ((unsigned int)colb[(jj * 8 + 3) * 520] << 16);
            pk.z = (unsigned int)colb[(jj * 8 + 4) * 520] | ((unsigned int)colb[(jj * 8 + 5) * 520] << 16);
            pk.w = (unsigned int)colb[(jj * 8 + 6) * 520] | ((unsigned int)colb[(jj * 8 + 7) * 520] << 16);
            *(uint4*)(ob + jj * 8) = pk;
        }
    }

    if (bid == 0) { norms[tid] = 0.0f; norms[tid + 256] = 0.0f; }
}

// kB: LDS-free full-T vlad contraction.
// Block (kq,n,dq): bid = kq*64 + n*8 + dq  (xbT d-slice siblings share XCD).
// Wave w: 16 d at dq*64 + w*16, 16 k at kq*16, all 2048 t.
__global__ __launch_bounds__(256) void kB(const unsigned short* __restrict__ xbT,
                                          const unsigned short* __restrict__ aTs,
                                          const float* __restrict__ asumP,
                                          const float* __restrict__ cent,
                                          float* __restrict__ vpre,
                                          float* __restrict__ norms) {
    __shared__ float sAs[16];
    const int tid = threadIdx.x;
    const int w = tid >> 6, lane = tid & 63;
    const int l = lane & 15, q = lane >> 4;
    const int bid = blockIdx.x;
    const int kq = bid >> 6, n = (bid >> 3) & 7, dq = bid & 7;
    const int k0 = kq * 16;
    const int dbase = dq * 64 + w * 16;

    if (tid < 16) sAs[tid] = 0.0f;
    __syncthreads();
    {   // asum reduce: 32 kA-blocks of this n, 16 k's
        const int kk = tid & 15, chunk = tid >> 4;  // chunk = w*4 + q
        float p = asumP[(size_t)(n * 32 + chunk) * 64 + k0 + kk]
                + asumP[(size_t)(n * 32 + 16 + chunk) * 64 + k0 + kk];
        p += __shfl_xor(p, 16, 64);
        p += __shfl_xor(p, 32, 64);
        if (q == 0) atomicAdd(&sAs[kk], p);
    }

    const unsigned short* ap = aTs + ((size_t)(n * KK + k0 + l)) * TT + q * 8;
    const unsigned short* bp = xbT + ((size_t)(n * DD + dbase + l)) * TT + q * 8;
    floatx4 a0 = {0.f, 0.f, 0.f, 0.f}, a1 = a0, a2 = a0, a3 = a0;
#pragma unroll
    for (int s = 0; s < 64; s += 4) {
        a0 = __builtin_amdgcn_mfma_f32_16x16x32_bf16(*(const short8*)(ap + (s + 0) * 32),
                                                     *(const short8*)(bp + (s + 0) * 32), a0, 0, 0, 0);
        a1 = __builtin_amdgcn_mfma_f32_16x16x32_bf16(*(const short8*)(ap + (s + 1) * 32),
                                                     *(const short8*)(bp + (s + 1) * 32), a1, 0, 0, 0);
        a2 = __builtin_amdgcn_mfma_f32_16x16x32_bf16(*(const short8*)(ap + (s + 2) * 32),
                                                     *(const short8*)(bp + (s + 2) * 32), a2, 0, 0, 0);
        a3 = __builtin_amdgcn_mfma_f32_16x16x32_bf16(*(const short8*)(ap + (s + 3) * 32),
                                                     *(const short8*)(bp + (s + 3) * 32), a3, 0, 0, 0);
    }
    floatx4 acc;
#pragma unroll
    for (int r = 0; r < 4; ++r) acc[r] = (a0[r] + a1[r]) + (a2[r] + a3[r]);

    __syncthreads();  // sAs ready

    const int d = dbase + l;
#pragma unroll
    for (int r = 0; r < 4; ++r) {
        int k = k0 + 4 * q + r;
        float val = acc[r] - sAs[4 * q + r] * cent[(size_t)k * DD + d];
        vpre[((size_t)(n * KK + k)) * DD + d] = val;
        float s2 = val * val;
#pragma unroll
        for (int msk = 1; msk <= 8; msk <<= 1) s2 += __shfl_xor(s2, msk, 64);
        if (l == 0) atomicAdd(&norms[n * KK + k], s2);
    }
}

// kC: out = vpre / (max(||v||,eps) * 8). Global norm over 64 intra-normalized
// clusters == 8 (deviation <1e-6 rel -> ~1e-8 abs on outputs).
__global__ __launch_bounds__(128) void kC(const float* __restrict__ vpre,
                                          const float* __restrict__ norms,
                                          float* __restrict__ out) {
    const int nk = blockIdx.x;
    const int tid = threadIdx.x;
    float nr = sqrtf(norms[nk]);
    float sc = 1.0f / (fmaxf(nr, EPS) * 8.0f);
    float4 v4 = ((const float4*)(vpre + (size_t)nk * DD))[tid];
    v4.x *= sc; v4.y *= sc; v4.z *= sc; v4.w *= sc;
    ((float4*)(out + (size_t)nk * DD))[tid] = v4;
}

extern "C" void kernel_launch(void* const* d_in, const int* in_sizes, int n_in,
                              void* d_out, int out_size, void* d_ws, size_t ws_size,
                              hipStream_t stream) {
    const float* x    = (const float*)d_in[0];
    const float* W    = (const float*)d_in[1];
    const float* b    = (const float*)d_in[2];
    const float* cent = (const float*)d_in[3];
    float* out = (float*)d_out;

    float* w = (float*)d_ws;
    unsigned short* xbT = (unsigned short*)(w + 0);
    unsigned short* aTs = (unsigned short*)(w + 4194304);
    float* vpre  = w + 4718592;
    float* asumP = w + 4980736;
    float* norms = w + 4997120;

    hipLaunchKernelGGL(kA, dim3(256), dim3(256), 0, stream, x, W, b, xbT, aTs, asumP, norms);
    hipLaunchKernelGGL(kB, dim3(256), dim3(256), 0, stream, xbT, aTs, asumP, cent, vpre, norms);
    hipLaunchKernelGGL(kC, dim3(512), dim3(128), 0, stream, vpre, norms, out);
}

// Round 8
// 103.940 us; speedup vs baseline: 1.5655x; 1.0747x over previous
//
#include <hip/hip_runtime.h>
#include <math.h>

#define EPS 1e-12f
#define NN 8
#define TT 2048
#define DD 512
#define KK 64

typedef short short8 __attribute__((ext_vector_type(8)));
typedef float floatx4 __attribute__((ext_vector_type(4)));

__device__ __forceinline__ unsigned short f2bf(float f) {
    unsigned int u = __float_as_uint(f);
    u += 0x7FFFu + ((u >> 16) & 1u);
    return (unsigned short)(u >> 16);
}
__device__ __forceinline__ unsigned int pack2(float a, float b) {
    return (unsigned int)f2bf(a) | ((unsigned int)f2bf(b) << 16);
}

// ---------------------------------------------------------------------------
// ws layout (float units):
//   xb    bf16 [N*T][D]   @ 0        (4194304)   raw x bf16, row-major
//   aTs   bf16 [N][K][T]  @ 4194304  (524288)    a * s_t
//   vpre  f32  [512nk][D] @ 4718592  (262144)
//   asumP f32  [256][64]  @ 4980736  (16384)
//   norms f32  [512]      @ 4997120  (512)
// total ~5.0 M floats = 20 MB
// ---------------------------------------------------------------------------

// kA: round-5-proven. W->bf16 LDS (fragment-packed) + L2-norm + assignment
// softmax. Writes xb row-major, aTs[k][t] = a*s_t, asumP; zeroes norms.
__global__ __launch_bounds__(256) void kA(const float* __restrict__ x,
                                          const float* __restrict__ W,
                                          const float* __restrict__ bias,
                                          unsigned short* __restrict__ xb,
                                          unsigned short* __restrict__ aTs,
                                          float* __restrict__ asumP,
                                          float* __restrict__ norms) {
    __shared__ unsigned short sW[32768];  // 64 KB, fragment-packed
    __shared__ float sRed[256];

    const int tid = threadIdx.x;
    const int bid = blockIdx.x;
    const int w = tid >> 6, lane = tid & 63;
    const int l = lane & 15, q = lane >> 4;
    const int row0 = bid * 64 + w * 16;
    const int row = row0 + l;
    const int n = row0 >> 11;
    const int tl0 = row0 & (TT - 1);

    const float* xr = x + (size_t)row * DD;
    unsigned short* xo = xb + (size_t)row * DD;
    short8 fragA[16];
    float ssq = 0.0f;
#pragma unroll
    for (int s = 0; s < 16; ++s) {
        float4 u0 = *(const float4*)(xr + s * 32 + q * 8);
        float4 u1 = *(const float4*)(xr + s * 32 + q * 8 + 4);
        ssq += u0.x*u0.x + u0.y*u0.y + u0.z*u0.z + u0.w*u0.w
             + u1.x*u1.x + u1.y*u1.y + u1.z*u1.z + u1.w*u1.w;
        uint4 pk;
        pk.x = pack2(u0.x, u0.y); pk.y = pack2(u0.z, u0.w);
        pk.z = pack2(u1.x, u1.y); pk.w = pack2(u1.z, u1.w);
        union { uint4 u; short8 s8; } cvt; cvt.u = pk;
        fragA[s] = cvt.s8;
        *(uint4*)(xo + s * 32 + q * 8) = pk;
    }

    // W -> LDS (fragment-packed: slot ((s*4+h)*64+lane) = 8 bf16)
    {
        const int sp = tid >> 4, hp = (tid >> 2) & 3, qp = tid & 3;
        const float* wsrc = W + (size_t)(hp * 16) * DD + sp * 32 + qp * 8;
        unsigned short* wdst = sW + (size_t)tid * 128;
#pragma unroll
        for (int j = 0; j < 16; ++j) {
            float4 u0 = *(const float4*)(wsrc + (size_t)j * DD);
            float4 u1 = *(const float4*)(wsrc + (size_t)j * DD + 4);
            uint4 pk;
            pk.x = pack2(u0.x, u0.y); pk.y = pack2(u0.z, u0.w);
            pk.z = pack2(u1.x, u1.y); pk.w = pack2(u1.z, u1.w);
            *(uint4*)(wdst + j * 8) = pk;
        }
    }

    ssq += __shfl_xor(ssq, 16, 64);
    ssq += __shfl_xor(ssq, 32, 64);
    float st = 1.0f / fmaxf(sqrtf(ssq), EPS);

    __syncthreads();  // sW ready

    floatx4 acc[4];
#pragma unroll
    for (int h = 0; h < 4; ++h) acc[h] = floatx4{0.f, 0.f, 0.f, 0.f};
#pragma unroll
    for (int s = 0; s < 16; ++s) {
#pragma unroll
        for (int h = 0; h < 4; ++h) {
            short8 wf = *(const short8*)(sW + ((size_t)((s * 4 + h) * 64) + lane) * 8);
            acc[h] = __builtin_amdgcn_mfma_f32_16x16x32_bf16(fragA[s], wf, acc[h], 0, 0, 0);
        }
    }

    float sr[4];
#pragma unroll
    for (int r = 0; r < 4; ++r) sr[r] = __shfl(st, 4 * q + r, 64);
    float bj[4];
#pragma unroll
    for (int h = 0; h < 4; ++h) bj[h] = bias[h * 16 + l];

    float av[4][4];
#pragma unroll
    for (int r = 0; r < 4; ++r) {
        float v0 = acc[0][r] * sr[r] + bj[0], v1 = acc[1][r] * sr[r] + bj[1];
        float v2 = acc[2][r] * sr[r] + bj[2], v3 = acc[3][r] * sr[r] + bj[3];
        float m = fmaxf(fmaxf(v0, v1), fmaxf(v2, v3));
#pragma unroll
        for (int msk = 1; msk <= 8; msk <<= 1) m = fmaxf(m, __shfl_xor(m, msk, 64));
        float e0 = __expf(v0 - m), e1 = __expf(v1 - m), e2 = __expf(v2 - m), e3 = __expf(v3 - m);
        float ss = e0 + e1 + e2 + e3;
#pragma unroll
        for (int msk = 1; msk <= 8; msk <<= 1) ss += __shfl_xor(ss, msk, 64);
        float inv = 1.0f / ss;
        av[0][r] = e0 * inv; av[1][r] = e1 * inv; av[2][r] = e2 * inv; av[3][r] = e3 * inv;
    }

    // aTs[n][k][t] = a * s_t
#pragma unroll
    for (int h = 0; h < 4; ++h) {
        uint2 p;
        p.x = pack2(av[h][0] * sr[0], av[h][1] * sr[1]);
        p.y = pack2(av[h][2] * sr[2], av[h][3] * sr[3]);
        *(uint2*)(aTs + ((size_t)(n * KK + h * 16 + l)) * TT + tl0 + 4 * q) = p;
    }

    // per-block unscaled-a k-sums
#pragma unroll
    for (int h = 0; h < 4; ++h) {
        float sh = av[h][0] + av[h][1] + av[h][2] + av[h][3];
        sh += __shfl_xor(sh, 16, 64);
        sh += __shfl_xor(sh, 32, 64);
        if (q == 0) sRed[w * 64 + h * 16 + l] = sh;
    }
    __syncthreads();
    if (tid < 64) {
        float s0 = sRed[tid] + sRed[64 + tid] + sRed[128 + tid] + sRed[192 + tid];
        asumP[(size_t)bid * 64 + tid] = s0;
    }

    if (bid == 0) { norms[tid] = 0.0f; norms[tid + 256] = 0.0f; }
}

// kB: full-T vlad contraction, part-free.
// bid = (kh*32 + dt)*8 + n  (bid%8 == n: same-n blocks share an XCD; aTs
// n-slice 0.5 MB + xb n-slice 2.1 MB fit the 4 MB per-XCD L2).
// Block: 32 k (kh), 16 d (dt), all 2048 t. Wave w owns t-quarter w*512 with
// wave-private double-buffered LDS x-tiles -> NO barriers in the main loop.
__global__ __launch_bounds__(256) void kB(const unsigned short* __restrict__ xb,
                                          const unsigned short* __restrict__ aTs,
                                          const float* __restrict__ asumP,
                                          const float* __restrict__ cent,
                                          float* __restrict__ vpre,
                                          float* __restrict__ norms) {
    __shared__ __align__(16) unsigned short sX[4][2][1024];  // [wave][buf][16d x 64t]
    __shared__ float sC[4][512];                              // [wave][32k x 16d]
    __shared__ float sAs[32];

    const int tid = threadIdx.x;
    const int w = tid >> 6, lane = tid & 63;
    const int l = lane & 15, q = lane >> 4;
    const int bid = blockIdx.x;
    const int n = bid & 7, dt = (bid >> 3) & 31, kh = bid >> 8;
    const int k0 = kh * 32;
    const int d0 = dt * 16;

    // asum for this block's 32 k (issued early, consumed in epilogue)
    float myAsum = 0.0f;
    if (tid < 32) {
#pragma unroll 16
        for (int c = 0; c < 32; ++c)
            myAsum += asumP[(size_t)(n * 32 + c) * 64 + k0 + tid];
    }

    const int tq0 = w * 512;
    const unsigned short* xbase = xb + ((size_t)(n * TT + tq0 + lane)) * DD + d0;
    const unsigned short* ap = aTs + ((size_t)(n * KK + k0 + l)) * TT + tq0 + q * 8;
    unsigned short* b0 = &sX[w][0][0];
    unsigned short* b1 = &sX[w][1][0];
    const int gsw = lane & 7;

    // slot(d, t) = d*64 + (((t>>3) ^ (d&7)) << 3) + (t&7): staging writes and
    // b128 frag reads both <=2-way bank aliasing (free).
#define STAGE(S, BUF)                                                          \
    {                                                                          \
        const unsigned short* p_ = xbase + (size_t)(S) * 64 * DD;              \
        unsigned short vals[16];                                               \
        *(uint4*)(vals) = *(const uint4*)(p_);                                 \
        *(uint4*)(vals + 8) = *(const uint4*)(p_ + 8);                         \
        _Pragma("unroll")                                                      \
        for (int e = 0; e < 16; ++e)                                           \
            (BUF)[e * 64 + ((((lane >> 3) ^ (e & 7))) << 3) + (lane & 7)] = vals[e]; \
    }

    floatx4 acc0 = {0.f, 0.f, 0.f, 0.f}, acc1 = acc0;

    STAGE(0, b0);
#pragma unroll
    for (int s = 0; s < 8; ++s) {
        unsigned short* cur = (s & 1) ? b1 : b0;
        unsigned short* nxt = (s & 1) ? b0 : b1;
        if (s < 7) STAGE(s + 1, nxt);
#pragma unroll
        for (int ks = 0; ks < 2; ++ks) {
            short8 bf = *(const short8*)(cur + ((l & 15) * 64 + ((((ks << 2) + q) ^ gsw) << 3)));
            short8 a0 = *(const short8*)(ap + s * 64 + ks * 32);
            short8 a1 = *(const short8*)(ap + 16 * TT + s * 64 + ks * 32);
            acc0 = __builtin_amdgcn_mfma_f32_16x16x32_bf16(a0, bf, acc0, 0, 0, 0);
            acc1 = __builtin_amdgcn_mfma_f32_16x16x32_bf16(a1, bf, acc1, 0, 0, 0);
        }
    }
#undef STAGE

    // ---- epilogue: cross-wave reduce, -asum*c, vpre + norms ----
#pragma unroll
    for (int r = 0; r < 4; ++r) {
        sC[w][(4 * q + r) * 16 + l] = acc0[r];
        sC[w][(16 + 4 * q + r) * 16 + l] = acc1[r];
    }
    if (tid < 32) sAs[tid] = myAsum;
    __syncthreads();

    const int e0 = tid * 2;
    const int kl = e0 >> 4, d = e0 & 15;
    float v0 = (sC[0][e0] + sC[1][e0]) + (sC[2][e0] + sC[3][e0]);
    float v1 = (sC[0][e0 + 1] + sC[1][e0 + 1]) + (sC[2][e0 + 1] + sC[3][e0 + 1]);
    float as = sAs[kl];
    const float* cp = cent + (size_t)(k0 + kl) * DD + d0 + d;
    v0 -= as * cp[0];
    v1 -= as * cp[1];
    *(float2*)(vpre + ((size_t)(n * KK + k0 + kl)) * DD + d0 + d) = make_float2(v0, v1);
    float s2 = v0 * v0 + v1 * v1;
    s2 += __shfl_xor(s2, 1, 64);
    s2 += __shfl_xor(s2, 2, 64);
    s2 += __shfl_xor(s2, 4, 64);
    if ((tid & 7) == 0) atomicAdd(&norms[n * KK + k0 + kl], s2);
}

// kC: out = vpre / (max(||v||,eps) * 8). Global norm over 64 intra-normalized
// clusters == 8 (deviation <1e-6 rel -> ~1e-8 abs on outputs).
__global__ __launch_bounds__(128) void kC(const float* __restrict__ vpre,
                                          const float* __restrict__ norms,
                                          float* __restrict__ out) {
    const int nk = blockIdx.x;
    const int tid = threadIdx.x;
    float nr = sqrtf(norms[nk]);
    float sc = 1.0f / (fmaxf(nr, EPS) * 8.0f);
    float4 v4 = ((const float4*)(vpre + (size_t)nk * DD))[tid];
    v4.x *= sc; v4.y *= sc; v4.z *= sc; v4.w *= sc;
    ((float4*)(out + (size_t)nk * DD))[tid] = v4;
}

extern "C" void kernel_launch(void* const* d_in, const int* in_sizes, int n_in,
                              void* d_out, int out_size, void* d_ws, size_t ws_size,
                              hipStream_t stream) {
    const float* x    = (const float*)d_in[0];
    const float* W    = (const float*)d_in[1];
    const float* b    = (const float*)d_in[2];
    const float* cent = (const float*)d_in[3];
    float* out = (float*)d_out;

    float* w = (float*)d_ws;
    unsigned short* xb  = (unsigned short*)(w + 0);
    unsigned short* aTs = (unsigned short*)(w + 4194304);
    float* vpre  = w + 4718592;
    float* asumP = w + 4980736;
    float* norms = w + 4997120;

    hipLaunchKernelGGL(kA, dim3(256), dim3(256), 0, stream, x, W, b, xb, aTs, asumP, norms);
    hipLaunchKernelGGL(kB, dim3(512), dim3(256), 0, stream, xb, aTs, asumP, cent, vpre, norms);
    hipLaunchKernelGGL(kC, dim3(512), dim3(128), 0, stream, vpre, norms, out);
}

// Round 10
// 95.252 us; speedup vs baseline: 1.7083x; 1.0912x over previous
//
#include <hip/hip_runtime.h>
#include <math.h>

#define EPS 1e-12f
#define NN 8
#define TT 2048
#define DD 512
#define KK 64

typedef short short8 __attribute__((ext_vector_type(8)));
typedef float floatx4 __attribute__((ext_vector_type(4)));

__device__ __forceinline__ unsigned short f2bf(float f) {
    unsigned int u = __float_as_uint(f);
    u += 0x7FFFu + ((u >> 16) & 1u);
    return (unsigned short)(u >> 16);
}
__device__ __forceinline__ unsigned int pack2(float a, float b) {
    return (unsigned int)f2bf(a) | ((unsigned int)f2bf(b) << 16);
}
__device__ __forceinline__ float bf2f_lo(unsigned int u) {
    return __uint_as_float(u << 16);
}
__device__ __forceinline__ float bf2f_hi(unsigned int u) {
    return __uint_as_float(u & 0xFFFF0000u);
}

// ---------------------------------------------------------------------------
// ws layout (float units):
//   xb     bf16 [N*T][D]        @ 0        (4194304)   raw x, bf16
//   aTs    bf16 [N][K][T]       @ 4194304  (524288)    a * s_t
//   part16 bf16 [8tc][512nk][D] @ 4718592  (1048576)   vlad partials, bf16
//   asumP  f32  [256blk][64k]   @ 5767168  (16384)     per-block unscaled a sums
// total 5783552 floats = 23.1 MB
// ---------------------------------------------------------------------------

// kA: fused W->bf16 (LDS, fragment-packed) + L2-norm + assignment softmax.
// Block = 64 t-rows (4 waves x 16 rows); grid 256 (1 block/CU).
// Writes xb (raw bf16 x), aTs[k][t] = a*s_t, asumP[block][k].
__global__ __launch_bounds__(256) void kA(const float* __restrict__ x,
                                          const float* __restrict__ W,
                                          const float* __restrict__ bias,
                                          unsigned short* __restrict__ xb,
                                          unsigned short* __restrict__ aTs,
                                          float* __restrict__ asumP) {
    // sW: fragment-packed Wb. Slot ((s*4+h)*64 + lane) holds
    // W[h*16 + (lane&15)][s*32 + (lane>>4)*8 .. +7] as 8 bf16 (16 B).
    __shared__ unsigned short sW[32768];  // 64 KB
    __shared__ float sRed[256];

    const int tid = threadIdx.x;

    const int w = tid >> 6, lane = tid & 63;
    const int l = lane & 15, q = lane >> 4;
    const int row0 = blockIdx.x * 64 + w * 16;
    const int row = row0 + l;
    const int n = row0 >> 11;
    const int tl0 = row0 & (TT - 1);

    const float* xr = x + (size_t)row * DD;
    unsigned short* xo = xb + (size_t)row * DD;
    short8 fragA[16];
    float ssq = 0.0f;
#pragma unroll
    for (int s = 0; s < 16; ++s) {
        float4 u0 = *(const float4*)(xr + s * 32 + q * 8);
        float4 u1 = *(const float4*)(xr + s * 32 + q * 8 + 4);
        ssq += u0.x*u0.x + u0.y*u0.y + u0.z*u0.z + u0.w*u0.w
             + u1.x*u1.x + u1.y*u1.y + u1.z*u1.z + u1.w*u1.w;
        uint4 pk;
        pk.x = pack2(u0.x, u0.y); pk.y = pack2(u0.z, u0.w);
        pk.z = pack2(u1.x, u1.y); pk.w = pack2(u1.z, u1.w);
        union { uint4 u; short8 s8; } cvt; cvt.u = pk;
        fragA[s] = cvt.s8;
        *(uint4*)(xo + s * 32 + q * 8) = pk;
    }

    // ---- W -> LDS prologue (L2-hot; 128 elems/thread) ----
    {
        const int sp = tid >> 4, hp = (tid >> 2) & 3, qp = tid & 3;
        const float* wsrc = W + (size_t)(hp * 16) * DD + sp * 32 + qp * 8;
        unsigned short* wdst = sW + (size_t)tid * 128;  // 16 slots * 8 shorts
#pragma unroll
        for (int j = 0; j < 16; ++j) {
            float4 u0 = *(const float4*)(wsrc + (size_t)j * DD);
            float4 u1 = *(const float4*)(wsrc + (size_t)j * DD + 4);
            uint4 pk;
            pk.x = pack2(u0.x, u0.y); pk.y = pack2(u0.z, u0.w);
            pk.z = pack2(u1.x, u1.y); pk.w = pack2(u1.z, u1.w);
            *(uint4*)(wdst + j * 8) = pk;
        }
    }

    ssq += __shfl_xor(ssq, 16, 64);
    ssq += __shfl_xor(ssq, 32, 64);
    float st = 1.0f / fmaxf(sqrtf(ssq), EPS);

    __syncthreads();  // sW ready

    // ---- logits MFMA: B-frags from LDS ----
    floatx4 acc[4];
#pragma unroll
    for (int h = 0; h < 4; ++h) acc[h] = floatx4{0.f, 0.f, 0.f, 0.f};
#pragma unroll
    for (int s = 0; s < 16; ++s) {
#pragma unroll
        for (int h = 0; h < 4; ++h) {
            short8 wf = *(const short8*)(sW + ((size_t)((s * 4 + h) * 64) + lane) * 8);
            acc[h] = __builtin_amdgcn_mfma_f32_16x16x32_bf16(fragA[s], wf, acc[h], 0, 0, 0);
        }
    }

    float sr[4];
#pragma unroll
    for (int r = 0; r < 4; ++r) sr[r] = __shfl(st, 4 * q + r, 64);
    float bj[4];
#pragma unroll
    for (int h = 0; h < 4; ++h) bj[h] = bias[h * 16 + l];

    float av[4][4];  // [h][r]
#pragma unroll
    for (int r = 0; r < 4; ++r) {
        float v0 = acc[0][r] * sr[r] + bj[0], v1 = acc[1][r] * sr[r] + bj[1];
        float v2 = acc[2][r] * sr[r] + bj[2], v3 = acc[3][r] * sr[r] + bj[3];
        float m = fmaxf(fmaxf(v0, v1), fmaxf(v2, v3));
#pragma unroll
        for (int msk = 1; msk <= 8; msk <<= 1) m = fmaxf(m, __shfl_xor(m, msk, 64));
        float e0 = __expf(v0 - m), e1 = __expf(v1 - m), e2 = __expf(v2 - m), e3 = __expf(v3 - m);
        float ss = e0 + e1 + e2 + e3;
#pragma unroll
        for (int msk = 1; msk <= 8; msk <<= 1) ss += __shfl_xor(ss, msk, 64);
        float inv = 1.0f / ss;
        av[0][r] = e0 * inv; av[1][r] = e1 * inv; av[2][r] = e2 * inv; av[3][r] = e3 * inv;
    }

    // aTs[n][k][t] = a * s_t  (t = tl0 + 4q + r, k = h*16 + l)
#pragma unroll
    for (int h = 0; h < 4; ++h) {
        uint2 p;
        p.x = pack2(av[h][0] * sr[0], av[h][1] * sr[1]);
        p.y = pack2(av[h][2] * sr[2], av[h][3] * sr[3]);
        *(uint2*)(aTs + ((size_t)(n * KK + h * 16 + l)) * TT + tl0 + 4 * q) = p;
    }

    // per-block unscaled-a k-sums -> asumP[bid][k]
#pragma unroll
    for (int h = 0; h < 4; ++h) {
        float sh = av[h][0] + av[h][1] + av[h][2] + av[h][3];
        sh += __shfl_xor(sh, 16, 64);
        sh += __shfl_xor(sh, 32, 64);
        if (q == 0) sRed[w * 64 + h * 16 + l] = sh;
    }
    __syncthreads();
    if (tid < 64) {
        float s0 = sRed[tid] + sRed[64 + tid] + sRed[128 + tid] + sRed[192 + tid];
        asumP[(size_t)blockIdx.x * 64 + tid] = s0;
    }
}

// kB: part16[tc][n*64+k][d] = sum_{t in 256-chunk} aTs[k][t] * xb[t][d]
// bid = dt*64 + (n*8 + tc): bid%8 == tc -> all 8 dt-blocks sharing an
// (n,tc) aTs/xb slice land on the same XCD (L2 reuse; aTs fetched once).
__global__ __launch_bounds__(256) void kB(const unsigned short* __restrict__ xb,
                                          const unsigned short* __restrict__ aTs,
                                          unsigned short* __restrict__ part16) {
    __shared__ unsigned char smem[17408];  // 2x4096 ushort staging | 64x68 f32 transpose
    unsigned short* sX0 = (unsigned short*)smem;
    unsigned short* sX1 = sX0 + 4096;
    float* sT = (float*)smem;

    const int tid = threadIdx.x;
    const int wv = tid >> 6, lane = tid & 63;
    const int l = lane & 15, q = lane >> 4;
    const int bid = blockIdx.x;
    const int low = bid & 63;
    const int n = low >> 3, tc = low & 7, dt = bid >> 6;

    const int ts = tid & 63, dq = tid >> 6;
    const unsigned short* xbase = xb + ((size_t)(n * TT + tc * 256)) * DD + dt * 64 + dq * 16;
    const int g = ts >> 3, t7 = ts & 7;

#define STAGE(S, BUF)                                                          \
    {                                                                          \
        const unsigned short* p_ = xbase + (size_t)((S) * 64 + ts) * DD;       \
        unsigned short vals[16];                                               \
        *(uint4*)(vals) = *(const uint4*)(p_);                                 \
        *(uint4*)(vals + 8) = *(const uint4*)(p_ + 8);                         \
        _Pragma("unroll")                                                      \
        for (int e = 0; e < 16; ++e) {                                         \
            int d_ = dq * 16 + e;                                              \
            (BUF)[d_ * 64 + ((g ^ (d_ & 7)) << 3) + t7] = vals[e];             \
        }                                                                      \
    }

    floatx4 acc[4];
#pragma unroll
    for (int nt = 0; nt < 4; ++nt) acc[nt] = floatx4{0.f, 0.f, 0.f, 0.f};
    const unsigned short* abase = aTs + ((size_t)(n * KK + wv * 16 + l)) * TT + tc * 256;

    STAGE(0, sX0);
    __syncthreads();
#pragma unroll
    for (int s = 0; s < 4; ++s) {
        unsigned short* cur = (s & 1) ? sX1 : sX0;
        unsigned short* nxt = (s & 1) ? sX0 : sX1;
        if (s < 3) {
            if (s == 0) STAGE(1, nxt)
            else if (s == 1) STAGE(2, nxt)
            else STAGE(3, nxt)
        }
#pragma unroll
        for (int kb = 0; kb < 2; ++kb) {
            short8 af = *(const short8*)(abase + s * 64 + kb * 32 + q * 8);
            int gg = q + 4 * kb;
#pragma unroll
            for (int nt = 0; nt < 4; ++nt) {
                int d = nt * 16 + l;
                short8 bf = *(const short8*)(cur + d * 64 + ((gg ^ (d & 7)) << 3));
                acc[nt] = __builtin_amdgcn_mfma_f32_16x16x32_bf16(af, bf, acc[nt], 0, 0, 0);
            }
        }
        __syncthreads();
    }
#undef STAGE

    // transpose C through LDS -> coalesced bf16 stores
#pragma unroll
    for (int nt = 0; nt < 4; ++nt)
#pragma unroll
        for (int r = 0; r < 4; ++r)
            sT[(wv * 16 + 4 * q + r) * 68 + nt * 16 + l] = acc[nt][r];
    __syncthreads();

    unsigned short* pbase = part16 + ((size_t)(tc * 512 + n * KK)) * DD + dt * 64;
    const int fq = tid & 15, kr = tid >> 4;
#pragma unroll
    for (int i = 0; i < 4; ++i) {
        int k = i * 16 + kr;
        float4 val = *(float4*)(sT + k * 68 + fq * 4);
        uint2 o;
        o.x = pack2(val.x, val.y);
        o.y = pack2(val.z, val.w);
        *(uint2*)(pbase + (size_t)k * DD + fq * 4) = o;
    }
}

// kC: asum = sum(asumP); val = sum_tc part16 - asum*c; intra-norm + global-norm
// fold -> out. Global norm over 64 intra-normalized clusters is exactly
// sqrt(64)=8 (each cluster contributes 1.0 +- <1e-6 rel).
__global__ __launch_bounds__(128) void kC(const unsigned short* __restrict__ part16,
                                          const float* __restrict__ asumP,
                                          const float* __restrict__ cent,
                                          float* __restrict__ out) {
    __shared__ float red[2];
    __shared__ float sAsum;
    const int nk = blockIdx.x;
    const int n = nk >> 6, k = nk & 63;
    const int tid = threadIdx.x;

    if (tid < 32) {
        float p = asumP[(size_t)(n * 32 + tid) * 64 + k];
#pragma unroll
        for (int m = 16; m >= 1; m >>= 1) p += __shfl_xor(p, m, 64);
        if (tid == 0) sAsum = p;
    }
    __syncthreads();
    float as = sAsum;

    float4 cc = ((const float4*)(cent + (size_t)k * DD))[tid];
    float4 a4 = make_float4(-as * cc.x, -as * cc.y, -as * cc.z, -as * cc.w);
#pragma unroll
    for (int tc = 0; tc < 8; ++tc) {
        uint2 p = ((const uint2*)(part16 + ((size_t)(tc * 512 + nk)) * DD))[tid];
        a4.x += bf2f_lo(p.x); a4.y += bf2f_hi(p.x);
        a4.z += bf2f_lo(p.y); a4.w += bf2f_hi(p.y);
    }
    float ssq = a4.x*a4.x + a4.y*a4.y + a4.z*a4.z + a4.w*a4.w;
#pragma unroll
    for (int m = 32; m >= 1; m >>= 1) ssq += __shfl_xor(ssq, m, 64);
    if ((tid & 63) == 0) red[tid >> 6] = ssq;
    __syncthreads();
    float nr = sqrtf(red[0] + red[1]);
    float sc = 1.0f / (fmaxf(nr, EPS) * 8.0f);
    a4.x *= sc; a4.y *= sc; a4.z *= sc; a4.w *= sc;
    ((float4*)(out + (size_t)nk * DD))[tid] = a4;
}

extern "C" void kernel_launch(void* const* d_in, const int* in_sizes, int n_in,
                              void* d_out, int out_size, void* d_ws, size_t ws_size,
                              hipStream_t stream) {
    const float* x    = (const float*)d_in[0];
    const float* W    = (const float*)d_in[1];
    const float* b    = (const float*)d_in[2];
    const float* cent = (const float*)d_in[3];
    float* out = (float*)d_out;

    float* w = (float*)d_ws;
    unsigned short* xb     = (unsigned short*)(w + 0);
    unsigned short* aTs    = (unsigned short*)(w + 4194304);
    unsigned short* part16 = (unsigned short*)(w + 4718592);
    float* asumP = w + 5767168;

    hipLaunchKernelGGL(kA, dim3(256), dim3(256), 0, stream, x, W, b, xb, aTs, asumP);
    hipLaunchKernelGGL(kB, dim3(512), dim3(256), 0, stream, xb, aTs, part16);
    hipLaunchKernelGGL(kC, dim3(512), dim3(128), 0, stream, part16, asumP, cent, out);
}